// Round 3
// baseline (169.348 us; speedup 1.0000x reference)
//
#include <hip/hip_runtime.h>
#include <hip/hip_bf16.h>
#include <math.h>

#define BATCH 16
#define CT    256   // total input channels = R*Cin
#define HW    64
#define OCH   64    // O
#define NK    4     // K kernels in bank
#define HP    66    // padded spatial

typedef __attribute__((ext_vector_type(4))) float  f32x4;
typedef __attribute__((ext_vector_type(8))) short  s16x8;
typedef __attribute__((ext_vector_type(4))) unsigned short u16x4;

#define GLOBAL_AS __attribute__((address_space(1)))
#define LDS_AS    __attribute__((address_space(3)))

// rot90 source-index tables: w[s] = base[rotsrc[k][s]]
__device__ __constant__ int c_rotsrc[4][9] = {
    {0,1,2,3,4,5,6,7,8},
    {2,5,8,1,4,7,0,3,6},
    {8,7,6,5,4,3,2,1,0},
    {6,3,0,7,4,1,8,5,2}
};

static __device__ inline unsigned short f2bf(float f) {
    union { __hip_bfloat16 h; unsigned short u; } cv;
    cv.h = __float2bfloat16(f);
    return cv.u;
}

// ---------------- kernel 1: fused transpose+pad+pool-partials ----------------
// grid (4 ciT, 66 padded-rows, 16 b), 256 threads.
// Writes xT[b][pr][cc][ci] (bf16, zero borders) and partial[b][r][ci] row sums.
__global__ __launch_bounds__(256) void xpose_pool(const float* __restrict__ x,
                                                  unsigned short* __restrict__ xT,
                                                  float* __restrict__ partial) {
    const int ci0 = blockIdx.x * 64;
    const int pr  = blockIdx.y;
    const int b   = blockIdx.z;
    const int t   = threadIdx.x;
    unsigned short* xrow = xT + ((size_t)(b*HP + pr))*HP*CT;

    if (pr == 0 || pr == HP-1) {            // zero top/bottom padded rows
        for (int u = t; u < HP*16; u += 256) {
            int c = u >> 4, q = u & 15;
            *(u16x4*)(xrow + c*CT + ci0 + q*4) = (u16x4)0;
        }
        return;
    }
    const int r = pr - 1;

    __shared__ unsigned short tile[64][68];
    const int cilL = t >> 4;        // 0..15
    const int c0   = (t & 15) * 4;  // col group
    #pragma unroll
    for (int i = 0; i < 4; ++i) {
        int cil = cilL + i*16;
        f32x4 v = *(const f32x4*)(x + (((size_t)(b*CT + ci0 + cil))*HW + r)*HW + c0);
        tile[cil][c0+0] = f2bf(v[0]);
        tile[cil][c0+1] = f2bf(v[1]);
        tile[cil][c0+2] = f2bf(v[2]);
        tile[cil][c0+3] = f2bf(v[3]);
        float s = v[0] + v[1] + v[2] + v[3];
        s += __shfl_xor(s, 1, 16);
        s += __shfl_xor(s, 2, 16);
        s += __shfl_xor(s, 4, 16);
        s += __shfl_xor(s, 8, 16);
        if ((t & 15) == 0)
            partial[((size_t)(b*HW) + r)*CT + ci0 + cil] = s;
    }
    __syncthreads();

    if (t < 32) {                    // zero left/right border columns
        int colp = (t >> 4) * (HP-1);
        int q    = t & 15;
        *(u16x4*)(xrow + colp*CT + ci0 + q*4) = (u16x4)0;
    }
    #pragma unroll
    for (int i = 0; i < 4; ++i) {
        int u = i*256 + t;           // 0..1023
        int c = u >> 4, cil0 = (u & 15) * 4;
        u16x4 w;
        w[0] = tile[cil0+0][c];
        w[1] = tile[cil0+1][c];
        w[2] = tile[cil0+2][c];
        w[3] = tile[cil0+3][c];
        *(u16x4*)(xrow + (c+1)*CT + ci0 + cil0) = w;
    }
}

// ---------------- kernel 2: reduce partials -> FC -> sigmoid ----------------
__global__ __launch_bounds__(256) void coeff_kernel(const float* __restrict__ partial,
                                                    const float* __restrict__ fc_w,
                                                    const float* __restrict__ fc_b,
                                                    float* __restrict__ coeffs) {
    const int b = blockIdx.x;
    const int t = threadIdx.x;
    const float* pp = partial + (size_t)b*HW*CT + t;
    float s = 0.f;
    #pragma unroll 8
    for (int r = 0; r < HW; ++r) s += pp[(size_t)r*CT];
    __shared__ float pool[CT];
    pool[t] = s * (1.f / (HW*HW));
    __syncthreads();
    const int w = t >> 6, l = t & 63;
    float d = 0.f;
    for (int c = l; c < CT; c += 64) d += pool[c] * fc_w[w*CT + c];
    for (int off = 32; off; off >>= 1) d += __shfl_down(d, off, 64);
    if (l == 0)
        coeffs[b*NK + w] = 1.f / (1.f + expf(-(d + fc_b[w])));
}

// ---------------- kernel 3: fused mix+rotate -> bf16 weights ----------------
// W[b][s][cig][co][8ci]; thread = (b, cig, co), writes 9 s16x8 (coalesced in co).
__global__ __launch_bounds__(256) void wbuild_kernel(const float* __restrict__ coeffs,
                                                     const float* __restrict__ bank,
                                                     unsigned short* __restrict__ Wb) {
    const int idx = blockIdx.x * 256 + threadIdx.x;  // 16*32*256 = 131072
    const int b   = idx >> 13;
    const int rem = idx & 8191;
    const int cig = rem >> 8;         // 0..31
    const int co  = rem & 255;
    const int ro  = co >> 6, o = co & 63;
    const int ri  = cig >> 3;
    const int kk  = (ro - ri) & 3;
    const int c0  = (cig & 7) * 8;

    const float cf0 = coeffs[b*NK+0], cf1 = coeffs[b*NK+1];
    const float cf2 = coeffs[b*NK+2], cf3 = coeffs[b*NK+3];

    int rs[9];
    #pragma unroll
    for (int s = 0; s < 9; ++s) rs[s] = c_rotsrc[kk][s];

    float basej[8][9];                // already rotated: basej[j][s_out]
    #pragma unroll
    for (int j = 0; j < 8; ++j) {
        const float* bp = bank + ((size_t)(o*64 + c0 + j))*9;
        #pragma unroll
        for (int s = 0; s < 9; ++s) {
            int src = rs[s];
            basej[j][s] = cf0*bp[src] + cf1*bp[36864+src]
                        + cf2*bp[2*36864+src] + cf3*bp[3*36864+src];
        }
    }
    #pragma unroll
    for (int s = 0; s < 9; ++s) {
        s16x8 w;
        #pragma unroll
        for (int j = 0; j < 8; ++j) w[j] = (short)f2bf(basej[j][s]);
        *(s16x8*)(Wb + ((((size_t)(b*9 + s)*32 + cig)*256 + co) << 3)) = w;
    }
}

// ---------------- kernel 4: MFMA implicit-GEMM conv ----------------
// grid (16 rowT, 4 coT, 16 b) = 1024 blocks, 256 threads (4 waves).
// block tile: 64 co x (4 rows x 64 cols); wave: 4 co-frags x 1 row x 4 col-frags.
__global__ __launch_bounds__(256, 4) void conv_mfma(
        const unsigned short* __restrict__ xT,
        const unsigned short* __restrict__ Wb,
        float* __restrict__ out) {
    const int b    = blockIdx.z;
    const int co0  = blockIdx.y * 64;
    const int r0   = blockIdx.x * 4;
    const int t    = threadIdx.x;
    const int wave = t >> 6;
    const int lane = t & 63;
    const int lo16 = lane & 15;
    const int hi4  = lane >> 4;

    // [6 rows][66 cols][32 ci] bf16 = 25344 B (+ clamp slack -> 25600 B)
    __shared__ __align__(16) unsigned short Xs[12800];

    f32x4 acc[4][4];
    #pragma unroll
    for (int f = 0; f < 4; ++f)
        #pragma unroll
        for (int p = 0; p < 4; ++p)
            acc[f][p] = (f32x4)0.f;

    for (int ch = 0; ch < 8; ++ch) {          // 32-ci chunk
        const int ci0 = ch * 32;
        __syncthreads();                       // previous chunk's reads done
        // ---- stage [6][66][32] tile via global_load_lds (16B units) ----
        #pragma unroll
        for (int it = 0; it < 7; ++it) {
            int ubase = it * 256 + wave * 64;  // wave-uniform
            if (ubase < 1584) {
                int u  = ubase + lane;
                int us = u > 1583 ? 1583 : u;  // clamp source only
                int pl = us >> 2, chunk = us & 3;
                int rr = pl / 66, cc = pl - rr * 66;
                const unsigned short* src = xT +
                    (((size_t)(b*HP + r0 + rr))*HP + cc)*CT + ci0 + chunk*8;
                __builtin_amdgcn_global_load_lds(
                    (const GLOBAL_AS void*)src,
                    (LDS_AS void*)(Xs + (size_t)ubase * 8),
                    16, 0, 0);
            }
        }
        __syncthreads();

        #pragma unroll
        for (int s = 0; s < 9; ++s) {
            const int dr = s / 3, dc = s % 3;
            // A-fragments: direct from global (L1/L2-resident)
            const unsigned short* wp = Wb +
                ((((size_t)(b*9 + s)*32) + ch*4 + hi4)*256 + co0 + lo16)*8;
            s16x8 a0 = *(const s16x8*)(wp + 0*128);
            s16x8 a1 = *(const s16x8*)(wp + 1*128);
            s16x8 a2 = *(const s16x8*)(wp + 2*128);
            s16x8 a3 = *(const s16x8*)(wp + 3*128);
            const int pbase = ((wave + dr)*66 + dc + lo16)*64 + hi4*16; // bytes
            #pragma unroll
            for (int cf = 0; cf < 4; ++cf) {
                s16x8 bf = *(const s16x8*)((const char*)Xs + pbase + cf*1024);
                acc[0][cf] = __builtin_amdgcn_mfma_f32_16x16x32_bf16(a0, bf, acc[0][cf], 0, 0, 0);
                acc[1][cf] = __builtin_amdgcn_mfma_f32_16x16x32_bf16(a1, bf, acc[1][cf], 0, 0, 0);
                acc[2][cf] = __builtin_amdgcn_mfma_f32_16x16x32_bf16(a2, bf, acc[2][cf], 0, 0, 0);
                acc[3][cf] = __builtin_amdgcn_mfma_f32_16x16x32_bf16(a3, bf, acc[3][cf], 0, 0, 0);
            }
        }
    }

    // ---- epilogue: D row = co (hi4*4+j), col = pixel (lo16) ----
    const int prow = r0 + wave;
    #pragma unroll
    for (int f = 0; f < 4; ++f)
        #pragma unroll
        for (int cf = 0; cf < 4; ++cf)
            #pragma unroll
            for (int j = 0; j < 4; ++j) {
                int co = co0 + f*16 + hi4*4 + j;
                out[(((size_t)(b*CT + co))*HW + prow)*HW + cf*16 + lo16] =
                    acc[f][cf][j];
            }
}

extern "C" void kernel_launch(void* const* d_in, const int* in_sizes, int n_in,
                              void* d_out, int out_size, void* d_ws, size_t ws_size,
                              hipStream_t stream) {
    const float* x    = (const float*)d_in[0];
    const float* bank = (const float*)d_in[1];
    const float* fc_w = (const float*)d_in[2];
    const float* fc_b = (const float*)d_in[3];
    float* out = (float*)d_out;

    // workspace layout (bytes)
    //   partial: 0        .. 1048576   (16*64*256 f32 row sums)
    //   coeffs : 1048576  .. 1048832   (64 f32)
    //   Wb     : 1049600  .. 19923968  (9437184 bf16)
    //   xT     : 19923968 .. 55608320  (17842176 bf16)
    char* wsb = (char*)d_ws;
    float* partial = (float*)wsb;
    float* coeffs  = (float*)(wsb + 1048576);
    unsigned short* Wb = (unsigned short*)(wsb + 1049600);
    unsigned short* xT = (unsigned short*)(wsb + 19923968);

    xpose_pool<<<dim3(4, HP, BATCH), 256, 0, stream>>>(x, xT, partial);
    coeff_kernel<<<BATCH, 256, 0, stream>>>(partial, fc_w, fc_b, coeffs);
    wbuild_kernel<<<(BATCH*32*256)/256, 256, 0, stream>>>(coeffs, bank, Wb);
    conv_mfma<<<dim3(16, 4, BATCH), 256, 0, stream>>>(xT, Wb, out);
}

// Round 4
// 104.338 us; speedup vs baseline: 1.6231x; 1.6231x over previous
//
#include <hip/hip_runtime.h>
#include <hip/hip_bf16.h>
#include <math.h>

#define BATCH 16
#define CT    256   // total input channels = R*Cin
#define HW    64
#define OCH   64    // O
#define NK    4     // K kernels in bank
#define HP    66    // padded spatial

typedef __attribute__((ext_vector_type(4))) float  f32x4;
typedef __attribute__((ext_vector_type(8))) short  s16x8;
typedef __attribute__((ext_vector_type(4))) unsigned short u16x4;

#define GLOBAL_AS __attribute__((address_space(1)))
#define LDS_AS    __attribute__((address_space(3)))

// rot90 source-index tables: w[s] = base[rotsrc[k][s]]
__device__ __constant__ int c_rotsrc[4][9] = {
    {0,1,2,3,4,5,6,7,8},
    {2,5,8,1,4,7,0,3,6},
    {8,7,6,5,4,3,2,1,0},
    {6,3,0,7,4,1,8,5,2}
};

static __device__ inline unsigned short f2bf(float f) {
    union { __hip_bfloat16 h; unsigned short u; } cv;
    cv.h = __float2bfloat16(f);
    return cv.u;
}

// ---------------- kernel 1: fused transpose+pad+pool-partials ----------------
// grid (4 ciT, 66 padded-rows, 16 b), 256 threads.
// Writes xT[b][pr][cc][ci] (bf16, zero borders) and partial[b][r][ci] row sums.
__global__ __launch_bounds__(256) void xpose_pool(const float* __restrict__ x,
                                                  unsigned short* __restrict__ xT,
                                                  float* __restrict__ partial) {
    const int ci0 = blockIdx.x * 64;
    const int pr  = blockIdx.y;
    const int b   = blockIdx.z;
    const int t   = threadIdx.x;
    unsigned short* xrow = xT + ((size_t)(b*HP + pr))*HP*CT;

    if (pr == 0 || pr == HP-1) {            // zero top/bottom padded rows
        for (int u = t; u < HP*16; u += 256) {
            int c = u >> 4, q = u & 15;
            *(u16x4*)(xrow + c*CT + ci0 + q*4) = (u16x4)0;
        }
        return;
    }
    const int r = pr - 1;

    __shared__ unsigned short tile[64][70];   // stride 70: breaks read conflicts
    const int cilL = t >> 4;        // 0..3
    const int c0   = (t & 15) * 4;  // col group
    #pragma unroll
    for (int i = 0; i < 4; ++i) {
        int cil = cilL + i*16;
        // wait: cil must cover 0..63: cilL in 0..15 for 256 threads
        (void)cil;
    }
    // recompute properly: 256 threads -> t>>4 in 0..15
    const int cilH = t >> 4;        // 0..15
    #pragma unroll
    for (int i = 0; i < 4; ++i) {
        int cil = cilH + i*16;
        f32x4 v = *(const f32x4*)(x + (((size_t)(b*CT + ci0 + cil))*HW + r)*HW + c0);
        tile[cil][c0+0] = f2bf(v[0]);
        tile[cil][c0+1] = f2bf(v[1]);
        tile[cil][c0+2] = f2bf(v[2]);
        tile[cil][c0+3] = f2bf(v[3]);
        float s = v[0] + v[1] + v[2] + v[3];
        s += __shfl_xor(s, 1, 16);
        s += __shfl_xor(s, 2, 16);
        s += __shfl_xor(s, 4, 16);
        s += __shfl_xor(s, 8, 16);
        if ((t & 15) == 0)
            partial[((size_t)(b*HW) + r)*CT + ci0 + cil] = s;
    }
    __syncthreads();

    if (t < 32) {                    // zero left/right border columns
        int colp = (t >> 4) * (HP-1);
        int q    = t & 15;
        *(u16x4*)(xrow + colp*CT + ci0 + q*4) = (u16x4)0;
    }
    #pragma unroll
    for (int i = 0; i < 4; ++i) {
        int u = i*256 + t;           // 0..1023
        int c = u >> 4, cil0 = (u & 15) * 4;
        u16x4 w;
        w[0] = tile[cil0+0][c];
        w[1] = tile[cil0+1][c];
        w[2] = tile[cil0+2][c];
        w[3] = tile[cil0+3][c];
        *(u16x4*)(xrow + (c+1)*CT + ci0 + cil0) = w;
    }
}

// ---------------- kernel 2: reduce partials -> FC -> sigmoid ----------------
__global__ __launch_bounds__(256) void coeff_kernel(const float* __restrict__ partial,
                                                    const float* __restrict__ fc_w,
                                                    const float* __restrict__ fc_b,
                                                    float* __restrict__ coeffs) {
    const int b = blockIdx.x;
    const int t = threadIdx.x;
    const float* pp = partial + (size_t)b*HW*CT + t;
    float s = 0.f;
    #pragma unroll 8
    for (int r = 0; r < HW; ++r) s += pp[(size_t)r*CT];
    __shared__ float pool[CT];
    pool[t] = s * (1.f / (HW*HW));
    __syncthreads();
    const int w = t >> 6, l = t & 63;
    float d = 0.f;
    for (int c = l; c < CT; c += 64) d += pool[c] * fc_w[w*CT + c];
    for (int off = 32; off; off >>= 1) d += __shfl_down(d, off, 64);
    if (l == 0)
        coeffs[b*NK + w] = 1.f / (1.f + expf(-(d + fc_b[w])));
}

// ---------------- kernel 3: batch-independent rotated bank ----------------
// bankRotP[k][rr][s][c][o] = bank[k][o][c][rotsrc[rr][s]]  (f32)
// grid 64 blocks x 256 threads; writes coalesced in o.
__global__ __launch_bounds__(256) void bankrot_kernel(const float* __restrict__ bank,
                                                      float* __restrict__ P) {
    const int idx = blockIdx.x * 256 + threadIdx.x;   // < 4*64*64 = 16384
    const int o = idx & 63;
    const int c = (idx >> 6) & 63;
    const int k = idx >> 12;
    const float* bp = bank + ((size_t)((k*OCH + o)*64 + c))*9;
    float v[9];
    #pragma unroll
    for (int s = 0; s < 9; ++s) v[s] = bp[s];
    #pragma unroll
    for (int rr = 0; rr < 4; ++rr)
        #pragma unroll
        for (int s = 0; s < 9; ++s)
            P[(size_t)(((k*4 + rr)*9 + s))*4096 + c*64 + o] = v[c_rotsrc[rr][s]];
}

// ---------------- kernel 4: coalesced mix -> bf16 weights ----------------
// W[b][s][cig][co][8ci]; grid (32 cig, 9 s) x 256 threads (co).
__global__ __launch_bounds__(256) void wbuild_kernel(const float* __restrict__ coeffs,
                                                     const float* __restrict__ P,
                                                     unsigned short* __restrict__ Wb) {
    const int cig = blockIdx.x;
    const int s   = blockIdx.y;
    const int co  = threadIdx.x;
    const int ro  = co >> 6;
    const int o   = co & 63;
    const int ri  = cig >> 3;
    const int rr  = (ro - ri) & 3;
    const int c8  = (cig & 7) * 8;

    float r[NK][8];
    #pragma unroll
    for (int k = 0; k < NK; ++k) {
        const float* pp = P + (size_t)(((k*4 + rr)*9 + s))*4096 + o;
        #pragma unroll
        for (int q = 0; q < 8; ++q)
            r[k][q] = pp[(c8 + q)*64];
    }
    #pragma unroll
    for (int b = 0; b < BATCH; ++b) {
        const float cf0 = coeffs[b*NK+0], cf1 = coeffs[b*NK+1];
        const float cf2 = coeffs[b*NK+2], cf3 = coeffs[b*NK+3];
        s16x8 w;
        #pragma unroll
        for (int q = 0; q < 8; ++q) {
            float v = cf0*r[0][q] + cf1*r[1][q] + cf2*r[2][q] + cf3*r[3][q];
            w[q] = (short)f2bf(v);
        }
        *(s16x8*)(Wb + ((((size_t)(b*9 + s)*32 + cig)*256 + co) << 3)) = w;
    }
}

// ---------------- kernel 5: MFMA implicit-GEMM conv ----------------
// 512 blocks (XCD-swizzled), 256 threads (4 waves).
// block tile: 256 co x (2 rows x 64 cols); wave: 128 co x 1 row x 64 px.
// Double-buffered LDS, prefetch-before-compute, one barrier per chunk.
#define CHUNK_UNITS 1056     // 4 rows x 66 cols x 32 ci x 2B / 16B
#define BUF_UNITS   1088     // + 32-unit clamp slack
__global__ __launch_bounds__(256, 2) void conv_mfma(
        const unsigned short* __restrict__ xT,
        const unsigned short* __restrict__ Wb,
        float* __restrict__ out) {
    const int bid = blockIdx.x;
    const int xcd = bid & 7;
    const int sub = bid >> 3;          // 0..63
    const int b   = xcd*2 + (sub & 1); // each XCD owns 2 batches
    const int rt  = sub >> 1;          // 0..31
    const int r0  = rt * 2;

    const int t    = threadIdx.x;
    const int w    = t >> 6;
    const int lane = t & 63;
    const int lo16 = lane & 15;
    const int hi4  = lane >> 4;
    const int wco  = w & 1;            // co half
    const int wrow = w >> 1;           // output row within tile
    const int co0  = wco * 128;

    __shared__ __align__(16) unsigned short Xs[2*BUF_UNITS*8];

    f32x4 acc[8][4];
    #pragma unroll
    for (int f = 0; f < 8; ++f)
        #pragma unroll
        for (int p = 0; p < 4; ++p)
            acc[f][p] = (f32x4)0.f;

#define STAGE(CH, BUF)                                                          \
    do {                                                                        \
        const int ci0_ = (CH) * 32;                                             \
        _Pragma("unroll")                                                       \
        for (int it = 0; it < 5; ++it) {                                        \
            int ubase = it*256 + w*64;                                          \
            if (ubase < CHUNK_UNITS) {                                          \
                int u  = ubase + lane;                                          \
                int us = u > (CHUNK_UNITS-1) ? (CHUNK_UNITS-1) : u;             \
                int pl = us >> 2, q = us & 3;                                   \
                int rr = pl / 66, cc = pl - rr*66;                              \
                const unsigned short* src = xT +                                \
                    (((size_t)(b*HP + r0 + rr))*HP + cc)*CT + ci0_ + q*8;       \
                __builtin_amdgcn_global_load_lds(                               \
                    (const GLOBAL_AS void*)src,                                 \
                    (LDS_AS void*)(Xs + (size_t)((BUF)*BUF_UNITS + ubase)*8),   \
                    16, 0, 0);                                                  \
            }                                                                   \
        }                                                                       \
    } while (0)

    STAGE(0, 0);

    for (int ch = 0; ch < 8; ++ch) {
        __syncthreads();                 // drains vmcnt: chunk ch staged
        if (ch < 7) STAGE(ch+1, (ch+1) & 1);
        const int bufoff = (ch & 1) * (BUF_UNITS*16);   // bytes

        #pragma unroll
        for (int s = 0; s < 9; ++s) {
            const int dr = s / 3, dc = s % 3;
            const unsigned short* wp = Wb +
                ((((size_t)(b*9 + s)*32) + ch*4 + hi4)*256 + co0 + lo16)*8;
            s16x8 a0 = *(const s16x8*)(wp + 0*128);
            s16x8 a1 = *(const s16x8*)(wp + 1*128);
            s16x8 a2 = *(const s16x8*)(wp + 2*128);
            s16x8 a3 = *(const s16x8*)(wp + 3*128);
            s16x8 a4 = *(const s16x8*)(wp + 4*128);
            s16x8 a5 = *(const s16x8*)(wp + 5*128);
            s16x8 a6 = *(const s16x8*)(wp + 6*128);
            s16x8 a7 = *(const s16x8*)(wp + 7*128);
            const int pbase = bufoff + ((wrow + dr)*66 + dc + lo16)*64 + hi4*16;
            #pragma unroll
            for (int cf = 0; cf < 4; ++cf) {
                s16x8 bf = *(const s16x8*)((const char*)Xs + pbase + cf*1024);
                acc[0][cf] = __builtin_amdgcn_mfma_f32_16x16x32_bf16(a0, bf, acc[0][cf], 0, 0, 0);
                acc[1][cf] = __builtin_amdgcn_mfma_f32_16x16x32_bf16(a1, bf, acc[1][cf], 0, 0, 0);
                acc[2][cf] = __builtin_amdgcn_mfma_f32_16x16x32_bf16(a2, bf, acc[2][cf], 0, 0, 0);
                acc[3][cf] = __builtin_amdgcn_mfma_f32_16x16x32_bf16(a3, bf, acc[3][cf], 0, 0, 0);
                acc[4][cf] = __builtin_amdgcn_mfma_f32_16x16x32_bf16(a4, bf, acc[4][cf], 0, 0, 0);
                acc[5][cf] = __builtin_amdgcn_mfma_f32_16x16x32_bf16(a5, bf, acc[5][cf], 0, 0, 0);
                acc[6][cf] = __builtin_amdgcn_mfma_f32_16x16x32_bf16(a6, bf, acc[6][cf], 0, 0, 0);
                acc[7][cf] = __builtin_amdgcn_mfma_f32_16x16x32_bf16(a7, bf, acc[7][cf], 0, 0, 0);
            }
        }
    }
#undef STAGE

    // ---- epilogue: D row = co (hi4*4+j), col = pixel (lo16) ----
    const int prow = r0 + wrow;
    #pragma unroll
    for (int f = 0; f < 8; ++f)
        #pragma unroll
        for (int cf = 0; cf < 4; ++cf)
            #pragma unroll
            for (int j = 0; j < 4; ++j) {
                int co = co0 + f*16 + hi4*4 + j;
                out[(((size_t)(b*CT + co))*HW + prow)*HW + cf*16 + lo16] =
                    acc[f][cf][j];
            }
}

extern "C" void kernel_launch(void* const* d_in, const int* in_sizes, int n_in,
                              void* d_out, int out_size, void* d_ws, size_t ws_size,
                              hipStream_t stream) {
    const float* x    = (const float*)d_in[0];
    const float* bank = (const float*)d_in[1];
    const float* fc_w = (const float*)d_in[2];
    const float* fc_b = (const float*)d_in[3];
    float* out = (float*)d_out;

    // workspace layout (bytes)
    //   partial  : 0        .. 1048576   (16*64*256 f32) — consumed by coeff,
    //   bankRotP : 0        .. 2359296   (589824 f32)    — overwrites partial AFTER coeff
    //   coeffs   : 2359296  .. 2359552   (64 f32)
    //   Wb       : 2360320  .. 21234688  (9437184 bf16)
    //   xT       : 21234688 .. 56919040  (17842176 bf16)
    char* wsb = (char*)d_ws;
    float* partial = (float*)wsb;
    float* Prot    = (float*)wsb;
    float* coeffs  = (float*)(wsb + 2359296);
    unsigned short* Wb = (unsigned short*)(wsb + 2360320);
    unsigned short* xT = (unsigned short*)(wsb + 21234688);

    xpose_pool<<<dim3(4, HP, BATCH), 256, 0, stream>>>(x, xT, partial);
    coeff_kernel<<<BATCH, 256, 0, stream>>>(partial, fc_w, fc_b, coeffs);
    bankrot_kernel<<<64, 256, 0, stream>>>(bank, Prot);
    wbuild_kernel<<<dim3(32, 9), 256, 0, stream>>>(coeffs, Prot, Wb);
    conv_mfma<<<512, 256, 0, stream>>>(xT, Wb, out);
}

// Round 5
// 100.208 us; speedup vs baseline: 1.6900x; 1.0412x over previous
//
#include <hip/hip_runtime.h>
#include <hip/hip_bf16.h>
#include <math.h>

#define BATCH 16
#define CT    256   // total input channels = R*Cin
#define HW    64
#define OCH   64    // O
#define NK    4     // K kernels in bank
#define HP    66    // padded spatial
#define NPIX  4356  // 66*66

typedef __attribute__((ext_vector_type(4))) float  f32x4;
typedef __attribute__((ext_vector_type(8))) short  s16x8;
typedef __attribute__((ext_vector_type(4))) unsigned short u16x4;

#define GLOBAL_AS __attribute__((address_space(1)))
#define LDS_AS    __attribute__((address_space(3)))

// rot90 source-index tables: w[s] = base[rotsrc[k][s]]
__device__ __constant__ int c_rotsrc[4][9] = {
    {0,1,2,3,4,5,6,7,8},
    {2,5,8,1,4,7,0,3,6},
    {8,7,6,5,4,3,2,1,0},
    {6,3,0,7,4,1,8,5,2}
};

static __device__ inline unsigned short f2bf(float f) {
    union { __hip_bfloat16 h; unsigned short u; } cv;
    cv.h = __float2bfloat16(f);
    return cv.u;
}

// ---------------- kernel 1: fused transpose+pad+pool-partials ----------------
// xTg[b][ciq(32)][pix(4356)][8ci] bf16, zero borders; partial[b][r][ci] row sums.
// grid (4 ciT, 66 padded-rows, 16 b), 256 threads.
__global__ __launch_bounds__(256) void xpose_pool(const float* __restrict__ x,
                                                  unsigned short* __restrict__ xTg,
                                                  float* __restrict__ partial) {
    const int ci0 = blockIdx.x * 64;
    const int g0  = ci0 >> 3;          // first of 8 ci-groups
    const int pr  = blockIdx.y;        // padded row 0..65
    const int b   = blockIdx.z;
    const int t   = threadIdx.x;

    if (pr == 0 || pr == HP-1) {       // zero top/bottom padded rows
        for (int u = t; u < 8*HP; u += 256) {
            int g = u / HP, c = u % HP;
            *(s16x8*)(xTg + ((((size_t)(b*32 + g0 + g))*NPIX) + pr*HP + c)*8) =
                (s16x8)(short)0;
        }
        return;
    }
    const int r = pr - 1;

    __shared__ unsigned short tile[64][70];
    const int cilH = t >> 4;        // 0..15
    const int c0   = (t & 15) * 4;  // col group
    #pragma unroll
    for (int i = 0; i < 4; ++i) {
        int cil = cilH + i*16;
        f32x4 v = *(const f32x4*)(x + (((size_t)(b*CT + ci0 + cil))*HW + r)*HW + c0);
        tile[cil][c0+0] = f2bf(v[0]);
        tile[cil][c0+1] = f2bf(v[1]);
        tile[cil][c0+2] = f2bf(v[2]);
        tile[cil][c0+3] = f2bf(v[3]);
        float s = v[0] + v[1] + v[2] + v[3];
        s += __shfl_xor(s, 1, 16);
        s += __shfl_xor(s, 2, 16);
        s += __shfl_xor(s, 4, 16);
        s += __shfl_xor(s, 8, 16);
        if ((t & 15) == 0)
            partial[((size_t)(b*HW) + r)*CT + ci0 + cil] = s;
    }
    __syncthreads();

    if (t < 16) {                      // zero left/right border pixels
        int g = t & 7, side = t >> 3;
        *(s16x8*)(xTg + ((((size_t)(b*32 + g0 + g))*NPIX) + pr*HP + side*(HP-1))*8) =
            (s16x8)(short)0;
    }
    #pragma unroll
    for (int i = 0; i < 4; ++i) {
        int u = i*256 + t;             // 0..1023
        int c = u & 63, cil0 = (u >> 6) * 4;
        u16x4 w;
        w[0] = tile[cil0+0][c];
        w[1] = tile[cil0+1][c];
        w[2] = tile[cil0+2][c];
        w[3] = tile[cil0+3][c];
        *(u16x4*)(xTg + ((((size_t)(b*32 + g0 + (cil0>>3)))*NPIX) + pr*HP + c + 1)*8
                  + (cil0 & 4)) = w;
    }
}

// ---------------- kernel 2: reduce partials -> FC -> sigmoid ----------------
__global__ __launch_bounds__(256) void coeff_kernel(const float* __restrict__ partial,
                                                    const float* __restrict__ fc_w,
                                                    const float* __restrict__ fc_b,
                                                    float* __restrict__ coeffs) {
    const int b = blockIdx.x;
    const int t = threadIdx.x;
    const float* pp = partial + (size_t)b*HW*CT + t;
    float s = 0.f;
    #pragma unroll 8
    for (int r = 0; r < HW; ++r) s += pp[(size_t)r*CT];
    __shared__ float pool[CT];
    pool[t] = s * (1.f / (HW*HW));
    __syncthreads();
    const int w = t >> 6, l = t & 63;
    float d = 0.f;
    for (int c = l; c < CT; c += 64) d += pool[c] * fc_w[w*CT + c];
    for (int off = 32; off; off >>= 1) d += __shfl_down(d, off, 64);
    if (l == 0)
        coeffs[b*NK + w] = 1.f / (1.f + expf(-(d + fc_b[w])));
}

// ---------------- kernel 3: batch-independent rotated bank ----------------
// bankRotP[k][rr][s][c][o] = bank[k][o][c][rotsrc[rr][s]]  (f32)
__global__ __launch_bounds__(256) void bankrot_kernel(const float* __restrict__ bank,
                                                      float* __restrict__ P) {
    const int idx = blockIdx.x * 256 + threadIdx.x;   // < 4*64*64 = 16384
    const int o = idx & 63;
    const int c = (idx >> 6) & 63;
    const int k = idx >> 12;
    const float* bp = bank + ((size_t)((k*OCH + o)*64 + c))*9;
    float v[9];
    #pragma unroll
    for (int s = 0; s < 9; ++s) v[s] = bp[s];
    #pragma unroll
    for (int rr = 0; rr < 4; ++rr)
        #pragma unroll
        for (int s = 0; s < 9; ++s)
            P[(size_t)(((k*4 + rr)*9 + s))*4096 + c*64 + o] = v[c_rotsrc[rr][s]];
}

// ---------------- kernel 4: coalesced mix -> bf16 weights ----------------
// W[b][s][cig][co][8ci]; grid (32 cig, 9 s) x 256 threads (co).
__global__ __launch_bounds__(256) void wbuild_kernel(const float* __restrict__ coeffs,
                                                     const float* __restrict__ P,
                                                     unsigned short* __restrict__ Wb) {
    const int cig = blockIdx.x;
    const int s   = blockIdx.y;
    const int co  = threadIdx.x;
    const int ro  = co >> 6;
    const int o   = co & 63;
    const int ri  = cig >> 3;
    const int rr  = (ro - ri) & 3;
    const int c8  = (cig & 7) * 8;

    float r[NK][8];
    #pragma unroll
    for (int k = 0; k < NK; ++k) {
        const float* pp = P + (size_t)(((k*4 + rr)*9 + s))*4096 + o;
        #pragma unroll
        for (int q = 0; q < 8; ++q)
            r[k][q] = pp[(c8 + q)*64];
    }
    #pragma unroll
    for (int b = 0; b < BATCH; ++b) {
        const float cf0 = coeffs[b*NK+0], cf1 = coeffs[b*NK+1];
        const float cf2 = coeffs[b*NK+2], cf3 = coeffs[b*NK+3];
        s16x8 w;
        #pragma unroll
        for (int q = 0; q < 8; ++q) {
            float v = cf0*r[0][q] + cf1*r[1][q] + cf2*r[2][q] + cf3*r[3][q];
            w[q] = (short)f2bf(v);
        }
        *(s16x8*)(Wb + ((((size_t)(b*9 + s)*32 + cig)*256 + co) << 3)) = w;
    }
}

// ---------------- kernel 5: MFMA implicit-GEMM conv ----------------
// 512 blocks (XCD-swizzled: 2 batches/XCD), 256 threads (4 waves).
// block tile: 256 co x (2 rows x 64 cols); wave: 64 co x 128 px.
// LDS tile [4 ciq][264 px][8 ci] -> conflict-free ds_read_b128 + coalesced staging.
#define CHUNK_UNITS 1056     // 4 ciq * 264 px (16B units)
#define BUF_UNITS   1088     // + clamp slack
__global__ __launch_bounds__(256, 2) void conv_mfma(
        const unsigned short* __restrict__ xTg,
        const unsigned short* __restrict__ Wb,
        float* __restrict__ out) {
    const int bid = blockIdx.x;
    const int b   = (bid & 7)*2 + ((bid >> 3) & 1);
    const int rt  = bid >> 4;          // 0..31
    const int r0  = rt * 2;

    const int t    = threadIdx.x;
    const int w    = t >> 6;           // wave -> 64-co quarter
    const int lane = t & 63;
    const int lo16 = lane & 15;
    const int hi4  = lane >> 4;

    __shared__ __align__(16) unsigned short Xs[2*BUF_UNITS*8];

    f32x4 acc[4][8];
    #pragma unroll
    for (int f = 0; f < 4; ++f)
        #pragma unroll
        for (int p = 0; p < 8; ++p)
            acc[f][p] = (f32x4)0.f;

#define STAGE(CH, BUF)                                                          \
    do {                                                                        \
        _Pragma("unroll")                                                       \
        for (int it = 0; it < 5; ++it) {                                        \
            int ubase = it*256 + w*64;                                          \
            if (ubase < CHUNK_UNITS) {                                          \
                int u  = ubase + lane;                                          \
                int us = u > (CHUNK_UNITS-1) ? (CHUNK_UNITS-1) : u;             \
                int q  = us / 264;                                              \
                int pl = us - q*264;                                            \
                const unsigned short* src = xTg +                               \
                    (((size_t)(b*32 + (CH)*4 + q))*NPIX + r0*HP + pl)*8;        \
                __builtin_amdgcn_global_load_lds(                               \
                    (const GLOBAL_AS void*)src,                                 \
                    (LDS_AS void*)(Xs + (size_t)((BUF)*BUF_UNITS + ubase)*8),   \
                    16, 0, 0);                                                  \
            }                                                                   \
        }                                                                       \
    } while (0)

    STAGE(0, 0);

    for (int ch = 0; ch < 8; ++ch) {
        __syncthreads();                 // staging of chunk ch complete
        if (ch < 7) STAGE(ch+1, (ch+1) & 1);
        // per-lane LDS base: ciq-slab (hi4) + pixel offset (lo16)
        const char* Xb = (const char*)Xs + (ch & 1)*(BUF_UNITS*16)
                         + hi4*(264*16) + lo16*16;

        #pragma unroll
        for (int s = 0; s < 9; ++s) {
            const int dr = s / 3, dc = s % 3;
            const unsigned short* wp = Wb +
                ((((size_t)(b*9 + s)*32) + ch*4 + hi4)*256 + w*64 + lo16)*8;
            s16x8 a0 = *(const s16x8*)(wp + 0*128);
            s16x8 a1 = *(const s16x8*)(wp + 1*128);
            s16x8 a2 = *(const s16x8*)(wp + 2*128);
            s16x8 a3 = *(const s16x8*)(wp + 3*128);
            #pragma unroll
            for (int p = 0; p < 8; ++p) {
                const int pixbase = ((p >> 2) + dr)*HP + dc + (p & 3)*16;
                s16x8 bf = *(const s16x8*)(Xb + pixbase*16);
                acc[0][p] = __builtin_amdgcn_mfma_f32_16x16x32_bf16(a0, bf, acc[0][p], 0, 0, 0);
                acc[1][p] = __builtin_amdgcn_mfma_f32_16x16x32_bf16(a1, bf, acc[1][p], 0, 0, 0);
                acc[2][p] = __builtin_amdgcn_mfma_f32_16x16x32_bf16(a2, bf, acc[2][p], 0, 0, 0);
                acc[3][p] = __builtin_amdgcn_mfma_f32_16x16x32_bf16(a3, bf, acc[3][p], 0, 0, 0);
            }
        }
    }
#undef STAGE

    // ---- epilogue: D row = co-within-16 (hi4*4+j), col = pixel (lo16) ----
    #pragma unroll
    for (int f = 0; f < 4; ++f)
        #pragma unroll
        for (int p = 0; p < 8; ++p) {
            const int row = r0 + (p >> 2);
            const int colb = (p & 3)*16 + lo16;
            #pragma unroll
            for (int j = 0; j < 4; ++j) {
                int co = w*64 + f*16 + hi4*4 + j;
                out[(((size_t)(b*CT + co))*HW + row)*HW + colb] = acc[f][p][j];
            }
        }
}

extern "C" void kernel_launch(void* const* d_in, const int* in_sizes, int n_in,
                              void* d_out, int out_size, void* d_ws, size_t ws_size,
                              hipStream_t stream) {
    const float* x    = (const float*)d_in[0];
    const float* bank = (const float*)d_in[1];
    const float* fc_w = (const float*)d_in[2];
    const float* fc_b = (const float*)d_in[3];
    float* out = (float*)d_out;

    // workspace layout (bytes)
    //   partial  : 0        .. 1048576   (16*64*256 f32) — consumed by coeff
    //   bankRotP : 0        .. 2359296   (589824 f32)    — overwrites partial AFTER coeff
    //   coeffs   : 2359296  .. 2359552   (64 f32)
    //   Wb       : 2360320  .. 21234688  (9437184 bf16)
    //   xTg      : 21234688 .. 56919040  (17842176 bf16)
    char* wsb = (char*)d_ws;
    float* partial = (float*)wsb;
    float* Prot    = (float*)wsb;
    float* coeffs  = (float*)(wsb + 2359296);
    unsigned short* Wb  = (unsigned short*)(wsb + 2360320);
    unsigned short* xTg = (unsigned short*)(wsb + 21234688);

    xpose_pool<<<dim3(4, HP, BATCH), 256, 0, stream>>>(x, xTg, partial);
    coeff_kernel<<<BATCH, 256, 0, stream>>>(partial, fc_w, fc_b, coeffs);
    bankrot_kernel<<<64, 256, 0, stream>>>(bank, Prot);
    wbuild_kernel<<<dim3(32, 9), 256, 0, stream>>>(coeffs, Prot, Wb);
    conv_mfma<<<512, 256, 0, stream>>>(xTg, Wb, out);
}